// Round 3
// baseline (84.895 us; speedup 1.0000x reference)
//
#include <hip/hip_runtime.h>

#define NB 4
#define NP 160
#define NL 128
#define NH 768
#define NT 9
#define NBLK (NB * NL)   // 512 blocks, one per (b,l)
#define L2E 1.4426950408889634f
#define LN2 0.6931471805599453f

struct WS {
    float    part[NBLK];   // per-block partial mins
    int      empty[NBLK];  // 1 = empty-but-masked row, consumer must fix
    unsigned counter;      // arrival counter (memset to 0 each call)
};

__global__ __launch_bounds__(256) void kfused(
    const float* __restrict__ embs, const void* __restrict__ p2w,
    const void* __restrict__ masks, const int* __restrict__ labels,
    const int* __restrict__ sentlen, const float* __restrict__ W,
    const float* __restrict__ bias, const float* __restrict__ start_t,
    const float* __restrict__ end_t, const float* __restrict__ trans,
    float* __restrict__ out, WS* __restrict__ ws)
{
    const int bl = blockIdx.x;        // 0..511
    const int b  = bl / NL;
    const int tid = threadIdx.x;

    __shared__ float wrsh[NH];
    __shared__ int   plist[NP];
    __shared__ int   cnt;
    __shared__ int   isint_sh;
    __shared__ float wmin[4];
    __shared__ int   amlast;

    // ---- bool-storage detect from masks[0..127 bytes] (batch 0 is all-true) ----
    if (tid < 64) {
        unsigned v = (tid < 32) ? ((const unsigned*)masks)[tid] : 0u;
        unsigned long long bad = __ballot(v > 1u);
        if (tid == 0) { isint_sh = (bad == 0ULL); cnt = 0; }
    }
    __syncthreads();
    const int is_int = isint_sh;

    // ---- partial min over this block's 960-float slice of embs ----
    {
        float m = 3.0e38f;
        const int base = bl * 960;                    // 512*960 = 491520 = NB*NP*NH
        for (int i = tid; i < 960; i += 256) m = fminf(m, embs[base + i]);
        #pragma unroll
        for (int o = 32; o > 0; o >>= 1) m = fminf(m, __shfl_down(m, o));
        if ((tid & 63) == 0) wmin[tid >> 6] = m;
    }

    // ---- piece list for this word ----
    if (tid < NP) {
        int v = is_int ? (((const int*)p2w)[bl * NP + tid] != 0)
                       : (((const unsigned char*)p2w)[bl * NP + tid] != 0);
        if (v) { int k = atomicAdd(&cnt, 1); plist[k] = tid; }
    }
    __syncthreads();
    if (tid == 0) ws->part[bl] = fminf(fminf(wmin[0], wmin[1]), fminf(wmin[2], wmin[3]));

    const int nc = cnt;
    const int mk = is_int ? (((const int*)masks)[bl] != 0)
                          : (((const unsigned char*)masks)[bl] != 0);
    float* logits = out + 1;

    if (nc == 0) {
        // word_reps = min_value (if masked) -> consumer fixes; else zeros -> bias only
        if (tid == 0) ws->empty[bl] = mk ? 1 : 0;
        if (tid < NT) logits[bl * NT + tid] = bias[tid];
    } else {
        if (tid == 0) ws->empty[bl] = 0;
        #pragma unroll
        for (int k = 0; k < 3; k++) {
            int h = tid + k * 256;
            float wr = -3.0e38f;               // min_value <= all values, so -inf init equiv
            for (int i = 0; i < nc; i++)
                wr = fmaxf(wr, embs[(b * NP + plist[i]) * NH + h]);
            wrsh[h] = mk ? wr : 0.f;
        }
        __syncthreads();
        const int w = tid >> 6, lane = tid & 63;
        for (int t = w; t < NT; t += 4) {
            float acc = 0.f;
            for (int h = lane; h < NH; h += 64) acc += wrsh[h] * W[h * NT + t];
            #pragma unroll
            for (int o = 32; o > 0; o >>= 1) acc += __shfl_down(acc, o);
            if (lane == 0) logits[bl * NT + t] = acc + bias[t];
        }
    }

    // ---- release + elect consumer ----
    __threadfence();
    __syncthreads();
    if (tid == 0) {
        unsigned old = __hip_atomic_fetch_add(&ws->counter, 1u, __ATOMIC_ACQ_REL,
                                              __HIP_MEMORY_SCOPE_AGENT);
        amlast = (old == NBLK - 1);
    }
    __syncthreads();
    if (!amlast) return;
    __threadfence();                              // acquire for all threads of consumer

    // =================== consumer: min-reduce, fixups, CRF ===================
    __shared__ float em_s[NB * NL * NT + 16];     // log2-scaled; pad for prefetch overread
    __shared__ float trs[NT * NT];
    __shared__ int   lab_s[NB * NL];
    __shared__ float llh[NB];
    __shared__ float colsum[NT];
    __shared__ float minv_sh;
    __shared__ float wmin2[4];

    {   // global min from 512 partials
        float m = fminf(ws->part[tid], ws->part[tid + 256]);
        #pragma unroll
        for (int o = 32; o > 0; o >>= 1) m = fminf(m, __shfl_down(m, o));
        if ((tid & 63) == 0) wmin2[tid >> 6] = m;
    }
    {   // colsum(W): wave w covers t = w, w+4, w+8
        const int w = tid >> 6, lane = tid & 63;
        for (int t = w; t < NT; t += 4) {
            float s = 0.f;
            for (int h = lane; h < NH; h += 64) s += W[h * NT + t];
            #pragma unroll
            for (int o = 32; o > 0; o >>= 1) s += __shfl_down(s, o);
            if (lane == 0) colsum[t] = s;
        }
    }
    __syncthreads();
    if (tid == 0) minv_sh = fminf(fminf(wmin2[0], wmin2[1]), fminf(wmin2[2], wmin2[3]));

    // stage logits (scaled), labels, transitions into LDS
    for (int i = tid; i < NB * NL * NT; i += 256) em_s[i] = logits[i] * L2E;
    for (int i = tid; i < NB * NL; i += 256)     lab_s[i] = labels[i];
    if (tid < NT * NT) trs[tid] = trans[tid] * L2E;
    __syncthreads();

    // fix empty-but-masked rows: logits = minv*colsum + b
    for (int r = tid; r < NBLK; r += 256) {
        if (ws->empty[r]) {
            float mv = minv_sh;
            for (int t = 0; t < NT; t++) {
                float v = mv * colsum[t] + bias[t];
                logits[r * NT + t] = v;
                em_s[r * NT + t]   = v * L2E;
            }
        }
    }
    __syncthreads();

    // ---- CRF: one wave per batch, lanes 0..8 hold alpha[tag] ----
    const int bb   = tid >> 6;
    const int lane = tid & 63;
    const int c    = (lane < NT) ? lane : 0;
    const int len  = sentlen[bb];                 // masks == arange < sent_length
    const float* em  = em_s + bb * NL * NT;
    const int*   lab = lab_s + bb * NL;

    // numerator: parallel over positions
    float nsum = 0.f;
    for (int i = 1 + lane; i < len; i += 64) {
        int tp = lab[i - 1], tc = lab[i];
        nsum += trs[tp * NT + tc] + em[i * NT + tc];
    }
    #pragma unroll
    for (int o = 32; o > 0; o >>= 1) nsum += __shfl_down(nsum, o);

    // alpha recursion
    float tcol[NT];
    #pragma unroll
    for (int p = 0; p < NT; p++) tcol[p] = trs[p * NT + c];

    float a    = start_t[c] * L2E + em[c];
    float em_c = em[NT + c];
    for (int i = 1; i < len; i++) {
        float em_nx = em[(i + 1) * NT + c];       // pad covers overread at i=len-1
        float v[NT];
        #pragma unroll
        for (int p = 0; p < NT; p++) v[p] = __shfl(a, p) + tcol[p];
        float mx = fmaxf(fmaxf(fmaxf(v[0], v[1]), v[2]),
                         fmaxf(fmaxf(fmaxf(v[3], v[4]), v[5]),
                               fmaxf(fmaxf(v[6], v[7]), v[8])));
        float e[NT];
        #pragma unroll
        for (int p = 0; p < NT; p++) {
            float d = v[p] - mx;
            asm("v_exp_f32 %0, %1" : "=v"(e[p]) : "v"(d));
        }
        float s = (((e[0] + e[1]) + (e[2] + e[3])) + ((e[4] + e[5]) + (e[6] + e[7]))) + e[8];
        float lg;
        asm("v_log_f32 %0, %1" : "=v"(lg) : "v"(s));
        a = mx + lg + em_c;
        em_c = em_nx;
    }

    float xv = a + end_t[c] * L2E;
    float dv[NT];
    #pragma unroll
    for (int p = 0; p < NT; p++) dv[p] = __shfl(xv, p);

    if (lane == 0) {
        float mx = fmaxf(fmaxf(fmaxf(dv[0], dv[1]), dv[2]),
                         fmaxf(fmaxf(fmaxf(dv[3], dv[4]), dv[5]),
                               fmaxf(fmaxf(dv[6], dv[7]), dv[8])));
        float s = 0.f;
        #pragma unroll
        for (int p = 0; p < NT; p++) {
            float d = dv[p] - mx, ee;
            asm("v_exp_f32 %0, %1" : "=v"(ee) : "v"(d));
            s += ee;
        }
        float lg;
        asm("v_log_f32 %0, %1" : "=v"(lg) : "v"(s));
        float den = mx + lg;
        float num = nsum + start_t[lab[0]] * L2E + em[lab[0]]
                         + end_t[lab[len - 1]] * L2E;
        llh[bb] = (num - den) * LN2;
    }
    __syncthreads();
    if (tid == 0) out[0] = -(llh[0] + llh[1] + llh[2] + llh[3]);
}

extern "C" void kernel_launch(void* const* d_in, const int* in_sizes, int n_in,
                              void* d_out, int out_size, void* d_ws, size_t ws_size,
                              hipStream_t stream) {
    const float* embs    = (const float*)d_in[0];
    const void*  p2w     = d_in[1];
    const void*  masks   = d_in[2];
    const int*   labels  = (const int*)d_in[3];
    const int*   sentlen = (const int*)d_in[4];
    const float* W       = (const float*)d_in[5];
    const float* bias    = (const float*)d_in[6];
    const float* start_t = (const float*)d_in[7];
    const float* end_t   = (const float*)d_in[8];
    const float* trans   = (const float*)d_in[9];

    float* out = (float*)d_out;        // out[0] = loss, out[1..] = logits (B,L,T)
    WS*    ws  = (WS*)d_ws;

    hipMemsetAsync(&ws->counter, 0, sizeof(unsigned), stream);  // capture-safe
    kfused<<<NBLK, 256, 0, stream>>>(embs, p2w, masks, labels, sentlen, W, bias,
                                     start_t, end_t, trans, out, ws);
}

// Round 4
// 41.501 us; speedup vs baseline: 2.0456x; 2.0456x over previous
//
#include <hip/hip_runtime.h>

#define NB 4
#define NP 160
#define NL 128
#define NH 768
#define NT 9
#define NBLK (NB * NL)   // 512, one block per (b,l)
#define L2E 1.4426950408889634f
#define LN2 0.6931471805599453f

struct WS {
    float part[NBLK];    // per-block partial mins of embs
    int   empty[NBLK];   // 1 = empty-but-masked row (needs minv fixup in kcrf)
};

__device__ __forceinline__ float rdlane(float v, int p) {
    return __int_as_float(__builtin_amdgcn_readlane(__float_as_int(v), p));
}

// ---------------- Kernel 1: word pooling + logits (+ slice-min, + dtype detect) -------
// One block per (b, l). 256 threads.
__global__ __launch_bounds__(256) void klogits(
    const float* __restrict__ embs, const void* __restrict__ p2w,
    const void* __restrict__ masks, const float* __restrict__ W,
    const float* __restrict__ bias, float* __restrict__ logits, WS* __restrict__ ws)
{
    const int bl = blockIdx.x;        // 0..511
    const int b  = bl / NL;
    const int tid = threadIdx.x;

    __shared__ float wrsh[NH];
    __shared__ int   plist[NP];
    __shared__ int   cnt;
    __shared__ int   isint_sh;
    __shared__ float wmin[4];

    // bool-storage detect from masks[0..127] (batch 0 is all-true by construction):
    // int32 bools -> first 32 u32 words are 1; byte bools -> words are 0x01010101 (>1).
    if (tid < 64) {
        unsigned v = (tid < 32) ? ((const unsigned*)masks)[tid] : 0u;
        unsigned long long bad = __ballot(v > 1u);
        if (tid == 0) { isint_sh = (bad == 0ULL); cnt = 0; }
    }
    __syncthreads();
    const int is_int = isint_sh;

    // partial min over this block's 960-float slice (512*960 = NB*NP*NH)
    {
        float m = 3.0e38f;
        const int base = bl * 960;
        for (int i = tid; i < 960; i += 256) m = fminf(m, embs[base + i]);
        #pragma unroll
        for (int o = 32; o > 0; o >>= 1) m = fminf(m, __shfl_down(m, o));
        if ((tid & 63) == 0) wmin[tid >> 6] = m;
    }

    // piece list for this word (order irrelevant for max)
    if (tid < NP) {
        int v = is_int ? (((const int*)p2w)[bl * NP + tid] != 0)
                       : (((const unsigned char*)p2w)[bl * NP + tid] != 0);
        if (v) { int k = atomicAdd(&cnt, 1); plist[k] = tid; }
    }
    __syncthreads();
    if (tid == 0) ws->part[bl] = fminf(fminf(wmin[0], wmin[1]), fminf(wmin[2], wmin[3]));

    const int nc = cnt;
    const int mk = is_int ? (((const int*)masks)[bl] != 0)
                          : (((const unsigned char*)masks)[bl] != 0);

    if (nc == 0) {
        // masked+empty -> word_reps = min_value (kcrf fixes); else zeros -> bias only
        if (tid == 0) ws->empty[bl] = mk ? 1 : 0;
        if (tid < NT) logits[bl * NT + tid] = bias[tid];
        return;
    }
    if (tid == 0) ws->empty[bl] = 0;

    #pragma unroll
    for (int k = 0; k < 3; k++) {
        int h = tid + k * 256;
        float wr = -3.0e38f;              // min_value <= all values, so -inf init equivalent
        for (int i = 0; i < nc; i++)
            wr = fmaxf(wr, embs[(b * NP + plist[i]) * NH + h]);
        wrsh[h] = mk ? wr : 0.f;
    }
    __syncthreads();

    const int w = tid >> 6, lane = tid & 63;
    for (int t = w; t < NT; t += 4) {
        float acc = 0.f;
        for (int h = lane; h < NH; h += 64) acc += wrsh[h] * W[h * NT + t];
        #pragma unroll
        for (int o = 32; o > 0; o >>= 1) acc += __shfl_down(acc, o);
        if (lane == 0) logits[bl * NT + t] = acc + bias[t];
    }
}

// ---------------- Kernel 2: min-reduce + empty fixup + CRF (log2 domain) --------------
// 1 block, 4 waves, one wave per batch; lanes 0..8 hold alpha[tag].
__global__ __launch_bounds__(256) void kcrf(
    float* __restrict__ logits, const int* __restrict__ labels,
    const int* __restrict__ sentlen, const float* __restrict__ W,
    const float* __restrict__ bias, const float* __restrict__ start_t,
    const float* __restrict__ end_t, const float* __restrict__ trans,
    WS* __restrict__ ws, float* __restrict__ loss_out)
{
    __shared__ float em_s[NB * NL * NT + 16];   // log2-scaled; pad for prefetch overread
    __shared__ float trs[NT * NT];
    __shared__ int   lab_s[NB * NL];
    __shared__ float llh[NB];
    __shared__ float colsum[NT];
    __shared__ float minv_sh;
    __shared__ float wmin[4];

    const int tid = threadIdx.x;

    {   // global min from 512 partials
        float m = fminf(ws->part[tid], ws->part[tid + 256]);
        #pragma unroll
        for (int o = 32; o > 0; o >>= 1) m = fminf(m, __shfl_down(m, o));
        if ((tid & 63) == 0) wmin[tid >> 6] = m;
    }
    {   // colsum(W): wave w covers t = w, w+4, w+8
        const int w = tid >> 6, lane = tid & 63;
        for (int t = w; t < NT; t += 4) {
            float s = 0.f;
            for (int h = lane; h < NH; h += 64) s += W[h * NT + t];
            #pragma unroll
            for (int o = 32; o > 0; o >>= 1) s += __shfl_down(s, o);
            if (lane == 0) colsum[t] = s;
        }
    }
    // stage logits (scaled), labels, transitions
    for (int i = tid; i < NB * NL * NT; i += 256) em_s[i] = logits[i] * L2E;
    for (int i = tid; i < NB * NL; i += 256)     lab_s[i] = labels[i];
    if (tid < NT * NT) trs[tid] = trans[tid] * L2E;
    __syncthreads();
    if (tid == 0) minv_sh = fminf(fminf(wmin[0], wmin[1]), fminf(wmin[2], wmin[3]));
    __syncthreads();

    // fix empty-but-masked rows: logits = minv*colsum + bias
    for (int r = tid; r < NBLK; r += 256) {
        if (ws->empty[r]) {
            float mv = minv_sh;
            for (int t = 0; t < NT; t++) {
                float v = mv * colsum[t] + bias[t];
                logits[r * NT + t] = v;
                em_s[r * NT + t]   = v * L2E;
            }
        }
    }
    __syncthreads();

    const int b    = tid >> 6;
    const int lane = tid & 63;
    const int c    = (lane < NT) ? lane : 0;    // lanes >= 9 mirror lane 0
    const int len  = sentlen[b];                // masks == arange < sent_length
    const float* em  = em_s + b * NL * NT;
    const int*   lab = lab_s + b * NL;

    // numerator: fully parallel over positions
    float nsum = 0.f;
    for (int i = 1 + lane; i < len; i += 64) {
        int tp = lab[i - 1], tc = lab[i];
        nsum += trs[tp * NT + tc] + em[i * NT + tc];
    }
    #pragma unroll
    for (int o = 32; o > 0; o >>= 1) nsum += __shfl_down(nsum, o);

    // alpha recursion: v_readlane broadcast (VALU) instead of ds_bpermute (DS pipe)
    float tcol[NT];
    #pragma unroll
    for (int p = 0; p < NT; p++) tcol[p] = trs[p * NT + c];

    float a    = start_t[c] * L2E + em[c];
    float em_c = em[NT + c];
    for (int i = 1; i < len; i++) {
        float em_nx = em[(i + 1) * NT + c];     // pad covers overread at i = len-1
        float v[NT];
        #pragma unroll
        for (int p = 0; p < NT; p++) v[p] = rdlane(a, p) + tcol[p];
        float mx = fmaxf(fmaxf(fmaxf(v[0], v[1]), v[2]),
                         fmaxf(fmaxf(fmaxf(v[3], v[4]), v[5]),
                               fmaxf(fmaxf(v[6], v[7]), v[8])));
        float e[NT];
        #pragma unroll
        for (int p = 0; p < NT; p++) {
            float d = v[p] - mx;
            asm("v_exp_f32 %0, %1" : "=v"(e[p]) : "v"(d));
        }
        float s = (((e[0] + e[1]) + (e[2] + e[3])) + ((e[4] + e[5]) + (e[6] + e[7]))) + e[8];
        float lg;
        asm("v_log_f32 %0, %1" : "=v"(lg) : "v"(s));
        a = mx + lg + em_c;
        em_c = em_nx;
    }

    float xv = a + end_t[c] * L2E;
    if (lane == 0) {
        float dv[NT];
        #pragma unroll
        for (int p = 0; p < NT; p++) dv[p] = rdlane(xv, p);
        float mx = fmaxf(fmaxf(fmaxf(dv[0], dv[1]), dv[2]),
                         fmaxf(fmaxf(fmaxf(dv[3], dv[4]), dv[5]),
                               fmaxf(fmaxf(dv[6], dv[7]), dv[8])));
        float s = 0.f;
        #pragma unroll
        for (int p = 0; p < NT; p++) {
            float d = dv[p] - mx, ee;
            asm("v_exp_f32 %0, %1" : "=v"(ee) : "v"(d));
            s += ee;
        }
        float lg;
        asm("v_log_f32 %0, %1" : "=v"(lg) : "v"(s));
        float den = mx + lg;
        float num = nsum + start_t[lab[0]] * L2E + em[lab[0]]
                         + end_t[lab[len - 1]] * L2E;
        llh[b] = (num - den) * LN2;
    }
    __syncthreads();
    if (tid == 0) loss_out[0] = -(llh[0] + llh[1] + llh[2] + llh[3]);
}

extern "C" void kernel_launch(void* const* d_in, const int* in_sizes, int n_in,
                              void* d_out, int out_size, void* d_ws, size_t ws_size,
                              hipStream_t stream) {
    const float* embs    = (const float*)d_in[0];
    const void*  p2w     = d_in[1];
    const void*  masks   = d_in[2];
    const int*   labels  = (const int*)d_in[3];
    const int*   sentlen = (const int*)d_in[4];
    const float* W       = (const float*)d_in[5];
    const float* bias    = (const float*)d_in[6];
    const float* start_t = (const float*)d_in[7];
    const float* end_t   = (const float*)d_in[8];
    const float* trans   = (const float*)d_in[9];

    float* out = (float*)d_out;        // out[0] = loss, out[1..] = logits (B,L,T)
    WS*    ws  = (WS*)d_ws;

    klogits<<<NBLK, 256, 0, stream>>>(embs, p2w, masks, W, bias, out + 1, ws);
    kcrf<<<1, 256, 0, stream>>>(out + 1, labels, sentlen, W, bias,
                                start_t, end_t, trans, ws, out);
}

// Round 5
// 33.941 us; speedup vs baseline: 2.5013x; 1.2227x over previous
//
#include <hip/hip_runtime.h>

#define NB 4
#define NP 160
#define NL 128
#define NH 768
#define NT 9
#define NBLK (NB * NL)   // 512, one block per (b,l)
#define L2E 1.4426950408889634f
#define LN2 0.6931471805599453f

struct WS {
    float lg[NBLK * NT];   // 16B-aligned logits copy for fast kcrf staging
    float part[NBLK];      // per-block partial mins of embs
    int   empty[NBLK];     // 1 = empty-but-masked row (needs minv fixup in kcrf)
};

__device__ __forceinline__ float rdlane(float v, int p) {
    return __int_as_float(__builtin_amdgcn_readlane(__float_as_int(v), p));
}

// Full-wave (64-lane) sum via DPP: row_shr 1/2/4/8 then row_bcast 15/31. Result in lane 63.
__device__ __forceinline__ float dpp_add(float x) {
    float t;
#define STEP(ctrl, rmask, bc) \
    t = __int_as_float(__builtin_amdgcn_update_dpp(0, __float_as_int(x), ctrl, rmask, 0xf, bc)); \
    x += t;
    STEP(0x111, 0xf, true)   // row_shr:1
    STEP(0x112, 0xf, true)   // row_shr:2
    STEP(0x114, 0xf, true)   // row_shr:4
    STEP(0x118, 0xf, true)   // row_shr:8
    STEP(0x142, 0xa, false)  // row_bcast:15 -> rows 1,3
    STEP(0x143, 0xc, false)  // row_bcast:31 -> rows 2,3
#undef STEP
    return x;                // lane 63 = full sum
}

// Full-wave min via DPP (masked lanes receive own value -> identity for fmin). Lane 63.
__device__ __forceinline__ float dpp_fmin(float x) {
    float t;
#define STEP(ctrl, rmask) \
    t = __int_as_float(__builtin_amdgcn_update_dpp(__float_as_int(x), __float_as_int(x), ctrl, rmask, 0xf, false)); \
    x = fminf(x, t);
    STEP(0x111, 0xf) STEP(0x112, 0xf) STEP(0x114, 0xf) STEP(0x118, 0xf)
    STEP(0x142, 0xa) STEP(0x143, 0xc)
#undef STEP
    return x;
}

// ---------------- Kernel 1: word pooling + logits (+ slice-min, + dtype detect) -------
__global__ __launch_bounds__(256) void klogits(
    const float* __restrict__ embs, const void* __restrict__ p2w,
    const void* __restrict__ masks, const float* __restrict__ W,
    const float* __restrict__ bias, float* __restrict__ out_logits, WS* __restrict__ ws)
{
    const int bl = blockIdx.x;        // 0..511
    const int b  = bl / NL;
    const int tid = threadIdx.x;

    __shared__ float wrsh[NH];
    __shared__ int   plist[NP];
    __shared__ int   cnt;
    __shared__ int   isint_sh;
    __shared__ float wmin[4];

    // ---- early independent loads ----
    const int base = bl * 960;        // 512*960 = NB*NP*NH
    float m = fminf(fminf(embs[base + tid], embs[base + tid + 256]), embs[base + tid + 512]);
    if (tid < 192) m = fminf(m, embs[base + tid + 768]);

    unsigned char pb = 0;
    if (tid < NP) pb = ((const unsigned char*)p2w)[bl * NP + tid];   // in-bounds either storage
    const unsigned char mkb = ((const unsigned char*)masks)[bl];

    // detect: masks word 0 (batch 0 all-true): int32 -> 1, bytes -> 0x01010101
    if (tid == 0) { isint_sh = (((const unsigned*)masks)[0] <= 1u); cnt = 0; }
    __syncthreads();
    const int is_int = isint_sh;

    int have = 0;
    if (tid < NP) have = is_int ? (((const int*)p2w)[bl * NP + tid] != 0) : (pb != 0);
    if (have) plist[atomicAdd(&cnt, 1)] = tid;

    m = dpp_fmin(m);
    if ((tid & 63) == 63) wmin[tid >> 6] = m;

    const int mk = is_int ? (((const int*)masks)[bl] != 0) : (mkb != 0);
    __syncthreads();
    if (tid == 0) ws->part[bl] = fminf(fminf(wmin[0], wmin[1]), fminf(wmin[2], wmin[3]));

    const int nc = cnt;
    if (nc == 0) {
        // masked+empty -> word_reps = min_value (kcrf fixes); else zeros -> bias only
        if (tid == 0) ws->empty[bl] = mk ? 1 : 0;
        if (tid < NT) { float v = bias[tid]; out_logits[bl * NT + tid] = v; ws->lg[bl * NT + tid] = v; }
        return;
    }
    if (tid == 0) ws->empty[bl] = 0;

    #pragma unroll
    for (int k = 0; k < 3; k++) {
        int h = tid + k * 256;
        float wr = -3.0e38f;          // min_value <= all values, so -inf init equivalent
        for (int i = 0; i < nc; i++)
            wr = fmaxf(wr, embs[(b * NP + plist[i]) * NH + h]);
        wrsh[h] = mk ? wr : 0.f;
    }
    __syncthreads();

    const int w = tid >> 6, lane = tid & 63;
    for (int t = w; t < NT; t += 4) {
        float acc = 0.f;
        #pragma unroll
        for (int j = 0; j < 12; j++) acc += wrsh[lane + j * 64] * W[(lane + j * 64) * NT + t];
        acc = dpp_add(acc);
        if (lane == 63) {
            float v = acc + bias[t];
            out_logits[bl * NT + t] = v;
            ws->lg[bl * NT + t]     = v;
        }
    }
}

// ---------------- Kernel 2: min-reduce + empty fixup + CRF (log2 domain) --------------
// 1 block, 4 waves, one wave per batch; lanes 0..8 hold alpha[tag].
__global__ __launch_bounds__(256) void kcrf(
    const int* __restrict__ labels, const int* __restrict__ sentlen,
    const float* __restrict__ W, const float* __restrict__ bias,
    const float* __restrict__ start_t, const float* __restrict__ end_t,
    const float* __restrict__ trans, WS* __restrict__ ws, float* __restrict__ out)
{
    __shared__ float em_s[NB * NL * NT + 16];   // RAW logits; pad for prefetch overread
    __shared__ float trs[NT * NT];              // log2-scaled
    __shared__ int   lab_s[NB * NL];
    __shared__ float llh[NB];
    __shared__ float colsum[NT];
    __shared__ float wmin[4];

    const int tid  = threadIdx.x;
    const int w    = tid >> 6;
    const int lane = tid & 63;

    // stage em (float4 from aligned ws copy), labels (int4), trans (scaled)
    {
        const float4* s4 = (const float4*)ws->lg;
        float4* d4 = (float4*)em_s;
        #pragma unroll
        for (int i = tid; i < (NB * NL * NT) / 4; i += 256) d4[i] = s4[i];
        if (tid < (NB * NL) / 4) ((int4*)lab_s)[tid] = ((const int4*)labels)[tid];
        if (tid < NT * NT) trs[tid] = trans[tid] * L2E;
    }
    {   // global min from 512 partials
        float mv = fminf(ws->part[tid], ws->part[tid + 256]);
        mv = dpp_fmin(mv);
        if (lane == 63) wmin[w] = mv;
    }
    for (int t = w; t < NT; t += 4) {   // colsum(W)
        float s = 0.f;
        #pragma unroll
        for (int j = 0; j < 12; j++) s += W[(lane + j * 64) * NT + t];
        s = dpp_add(s);
        if (lane == 63) colsum[t] = s;
    }
    __syncthreads();
    const float minv = fminf(fminf(wmin[0], wmin[1]), fminf(wmin[2], wmin[3]));

    // fix empty-but-masked rows: logits = minv*colsum + bias (LDS + final global)
    for (int r = tid; r < NBLK; r += 256) {
        if (ws->empty[r]) {
            #pragma unroll
            for (int t = 0; t < NT; t++) {
                float v = fmaf(minv, colsum[t], bias[t]);
                em_s[r * NT + t]   = v;
                out[1 + r * NT + t] = v;
            }
        }
    }
    __syncthreads();

    const int b   = w;
    const int c   = (lane < NT) ? lane : 0;     // lanes >= 9 mirror lane 0
    const int len = sentlen[b];                 // masks == arange < sent_length
    const float* em  = em_s + b * NL * NT;
    const int*   lab = lab_s + b * NL;

    // numerator: fully parallel over positions, DPP reduce
    float nsum = 0.f;
    for (int i = 1 + lane; i < len; i += 64) {
        int tp = lab[i - 1], tc = lab[i];
        nsum = fmaf(em[i * NT + tc], L2E, nsum + trs[tp * NT + tc]);
    }
    nsum = dpp_add(nsum);
    const float nsum_all = rdlane(nsum, 63);

    // alpha recursion (log2 domain, shift by v0 instead of max)
    float tcol[NT];
    #pragma unroll
    for (int p = 0; p < NT; p++) tcol[p] = trs[p * NT + c];

    float a    = fmaf(em[c], L2E, start_t[c] * L2E);
    float em_c = em[NT + c];
    for (int i = 1; i < len; i++) {
        float em_nx = em[(i + 1) * NT + c];     // pad covers overread at i = len-1
        float v0 = rdlane(a, 0) + tcol[0];
        float e[8];
        #pragma unroll
        for (int p = 1; p < NT; p++) {
            float d = (rdlane(a, p) + tcol[p]) - v0;
            asm("v_exp_f32 %0, %1" : "=v"(e[p - 1]) : "v"(d));
        }
        float s = 1.0f + (((e[0] + e[1]) + (e[2] + e[3])) + ((e[4] + e[5]) + (e[6] + e[7])));
        float lg;
        asm("v_log_f32 %0, %1" : "=v"(lg) : "v"(s));
        a = fmaf(em_c, L2E, v0 + lg);
        em_c = em_nx;
    }

    float xv = a + end_t[c] * L2E;
    if (lane == 0) {
        float dv[NT];
        #pragma unroll
        for (int p = 0; p < NT; p++) dv[p] = rdlane(xv, p);
        float mx = fmaxf(fmaxf(fmaxf(dv[0], dv[1]), dv[2]),
                         fmaxf(fmaxf(fmaxf(dv[3], dv[4]), dv[5]),
                               fmaxf(fmaxf(dv[6], dv[7]), dv[8])));
        float s = 0.f;
        #pragma unroll
        for (int p = 0; p < NT; p++) {
            float d = dv[p] - mx, ee;
            asm("v_exp_f32 %0, %1" : "=v"(ee) : "v"(d));
            s += ee;
        }
        float lg;
        asm("v_log_f32 %0, %1" : "=v"(lg) : "v"(s));
        float den = mx + lg;
        int   t0  = lab[0];
        float num = fmaf(em[t0], L2E, nsum_all + start_t[t0] * L2E + end_t[lab[len - 1]] * L2E);
        llh[b] = (num - den) * LN2;
    }
    __syncthreads();
    if (tid == 0) out[0] = -(llh[0] + llh[1] + llh[2] + llh[3]);
}

extern "C" void kernel_launch(void* const* d_in, const int* in_sizes, int n_in,
                              void* d_out, int out_size, void* d_ws, size_t ws_size,
                              hipStream_t stream) {
    const float* embs    = (const float*)d_in[0];
    const void*  p2w     = d_in[1];
    const void*  masks   = d_in[2];
    const int*   labels  = (const int*)d_in[3];
    const int*   sentlen = (const int*)d_in[4];
    const float* W       = (const float*)d_in[5];
    const float* bias    = (const float*)d_in[6];
    const float* start_t = (const float*)d_in[7];
    const float* end_t   = (const float*)d_in[8];
    const float* trans   = (const float*)d_in[9];

    float* out = (float*)d_out;        // out[0] = loss, out[1..] = logits (B,L,T)
    WS*    ws  = (WS*)d_ws;

    klogits<<<NBLK, 256, 0, stream>>>(embs, p2w, masks, W, bias, out + 1, ws);
    kcrf<<<1, 256, 0, stream>>>(labels, sentlen, W, bias, start_t, end_t, trans, ws, out);
}